// Round 10
// baseline (112.650 us; speedup 1.0000x reference)
//
#include <hip/hip_runtime.h>
#include <math.h>

#define K_TOP   8
#define EPS_F   1e-8f
#define T_DIM   2048
#define H_DIM   1024
#define NHEADS  16

typedef float f4 __attribute__((ext_vector_type(4)));

// shuffle-only top-8 with lowest-index tie-break + renorm scale
__device__ __forceinline__ void topk8(const f4 accv[8], int lane,
                                      float wvv[K_TOP], int wii[K_TOP],
                                      float& scale)
{
    float mybv = -INFINITY;
    int   mybi = 0x7fffffff;
    #pragma unroll
    for (int s = 0; s < 32; ++s) {
        const float val = accv[s >> 2][s & 3];
        if (val > mybv) { mybv = val; mybi = 256 * (s >> 2) + 4 * lane + (s & 3); }
    }
    unsigned mask = 0;

    for (int k = 0; k < K_TOP; ++k) {
        float bv = mybv;
        int   bi = mybi;
        #pragma unroll
        for (int off = 32; off > 0; off >>= 1) {
            const float ov = __shfl_down(bv, off);
            const int   oi = __shfl_down(bi, off);
            if (ov > bv || (ov == bv && oi < bi)) { bv = ov; bi = oi; }
        }
        bv = __shfl(bv, 0);
        bi = __shfl(bi, 0);
        wvv[k] = bv;
        wii[k] = bi;
        if (lane == ((bi >> 2) & 63)) {
            mask |= 1u << (4 * (bi >> 8) + (bi & 3));
            mybv = -INFINITY;
            mybi = 0x7fffffff;
            #pragma unroll
            for (int s = 0; s < 32; ++s) {
                const float val = ((mask >> s) & 1u) ? -INFINITY : accv[s >> 2][s & 3];
                if (val > mybv) { mybv = val; mybi = 256 * (s >> 2) + 4 * lane + (s & 3); }
            }
        }
    }

    const float inv16 = 1.0f / (float)NHEADS;
    float wsum = 0.0f;
    #pragma unroll
    for (int k = 0; k < K_TOP; ++k) wsum += wvv[k];
    const float denom = fmaxf(wsum * inv16, EPS_F);
    scale = inv16 / denom;
}

// One wave per PAIR of rows, software-pipelined:
//   stream row0 -> topk row0 -> [stream row1 || gather row0] -> write out0
//   -> topk row1 -> gather row1 -> write out1
// Only half the gather burst is exposed at kernel end.
__global__ __launch_bounds__(256, 2) void ctma_pipe_kernel(
    const float* __restrict__ mlp,   // [B, T, H]
    const float* __restrict__ attn,  // [B, Hh, T, T]
    float* __restrict__ out)         // [B, T, H]
{
    const int lane  = threadIdx.x & 63;
    const int wv_id = threadIdx.x >> 6;
    const int pair  = blockIdx.x * 4 + wv_id;   // 0..2047
    const int row0  = pair * 2;
    const int b     = row0 >> 11;

    const f4* a4 = reinterpret_cast<const f4*>(
        attn + (size_t)b * NHEADS * T_DIM * T_DIM + (size_t)(row0 & (T_DIM - 1)) * T_DIM);
    const size_t hs4 = (size_t)T_DIM * T_DIM / 4;
    const f4* mlp4 = reinterpret_cast<const f4*>(mlp)
                   + (size_t)b * T_DIM * (H_DIM / 4);

    f4 accv[8], tA[4], tB[4];

    // =========== stream row0 (32 half-head chunks, double-buffered) ===========
    #pragma unroll
    for (int j = 0; j < 8; ++j) accv[j] = (f4)(0.0f);
    #pragma unroll
    for (int j = 0; j < 4; ++j)
        tA[j] = __builtin_nontemporal_load(&a4[64 * j + lane]);

    #pragma unroll
    for (int c = 0; c < 32; ++c) {
        const int accbase = (c & 1) * 4;
        if (c + 1 < 32) {
            const f4* hp = a4 + (size_t)((c + 1) >> 1) * hs4 + ((c + 1) & 1) * 256;
            if (c & 1) {
                #pragma unroll
                for (int j = 0; j < 4; ++j)
                    tA[j] = __builtin_nontemporal_load(&hp[64 * j + lane]);
            } else {
                #pragma unroll
                for (int j = 0; j < 4; ++j)
                    tB[j] = __builtin_nontemporal_load(&hp[64 * j + lane]);
            }
        }
        if (c & 1) {
            #pragma unroll
            for (int j = 0; j < 4; ++j) accv[accbase + j] += tB[j];
        } else {
            #pragma unroll
            for (int j = 0; j < 4; ++j) accv[accbase + j] += tA[j];
        }
    }

    // =========== topk row0 ===========
    float wvv0[K_TOP]; int wii0[K_TOP]; float scale0;
    topk8(accv, lane, wvv0, wii0, scale0);

    // =========== stream row1 with gather row0 interleaved ===========
    const f4* a4r1 = a4 + 512;   // row0+1: +2048 floats
    #pragma unroll
    for (int j = 0; j < 8; ++j) accv[j] = (f4)(0.0f);

    f4 g[4];
    f4 o0[4];
    #pragma unroll
    for (int j = 0; j < 4; ++j) o0[j] = (f4)(0.0f);

    #pragma unroll
    for (int j = 0; j < 4; ++j)
        tA[j] = __builtin_nontemporal_load(&a4r1[64 * j + lane]);

    #pragma unroll
    for (int c = 0; c < 32; ++c) {
        const int accbase = (c & 1) * 4;
        // prefetch next stream chunk
        if (c + 1 < 32) {
            const f4* hp = a4r1 + (size_t)((c + 1) >> 1) * hs4 + ((c + 1) & 1) * 256;
            if (c & 1) {
                #pragma unroll
                for (int j = 0; j < 4; ++j)
                    tA[j] = __builtin_nontemporal_load(&hp[64 * j + lane]);
            } else {
                #pragma unroll
                for (int j = 0; j < 4; ++j)
                    tB[j] = __builtin_nontemporal_load(&hp[64 * j + lane]);
            }
        }
        // issue gather row k at c = 4k (cacheable loads)
        if ((c & 3) == 0) {
            const int k = c >> 2;
            const f4* src = mlp4 + (size_t)wii0[k] * (H_DIM / 4);
            #pragma unroll
            for (int j = 0; j < 4; ++j)
                g[j] = src[lane + 64 * j];
        }
        // accumulate stream chunk c
        if (c & 1) {
            #pragma unroll
            for (int j = 0; j < 4; ++j) accv[accbase + j] += tB[j];
        } else {
            #pragma unroll
            for (int j = 0; j < 4; ++j) accv[accbase + j] += tA[j];
        }
        // consume gather row k at c = 4k+2
        if ((c & 3) == 2) {
            const int k = c >> 2;
            const float w = wvv0[k] * scale0;
            #pragma unroll
            for (int j = 0; j < 4; ++j) o0[j] += w * g[j];
        }
    }

    // write out row0
    {
        f4* out4 = reinterpret_cast<f4*>(out) + (size_t)row0 * (H_DIM / 4);
        #pragma unroll
        for (int j = 0; j < 4; ++j)
            __builtin_nontemporal_store(o0[j], &out4[lane + 64 * j]);
    }

    // =========== topk row1 + gather row1 (exposed) ===========
    float wvv1[K_TOP]; int wii1[K_TOP]; float scale1;
    topk8(accv, lane, wvv1, wii1, scale1);

    f4 o1[4];
    #pragma unroll
    for (int j = 0; j < 4; ++j) o1[j] = (f4)(0.0f);
    #pragma unroll
    for (int k = 0; k < K_TOP; ++k) {
        const float w = wvv1[k] * scale1;
        const f4* src = mlp4 + (size_t)wii1[k] * (H_DIM / 4);
        #pragma unroll
        for (int j = 0; j < 4; ++j)
            o1[j] += w * src[lane + 64 * j];
    }
    {
        f4* out4 = reinterpret_cast<f4*>(out) + (size_t)(row0 + 1) * (H_DIM / 4);
        #pragma unroll
        for (int j = 0; j < 4; ++j)
            __builtin_nontemporal_store(o1[j], &out4[lane + 64 * j]);
    }
}

extern "C" void kernel_launch(void* const* d_in, const int* in_sizes, int n_in,
                              void* d_out, int out_size, void* d_ws, size_t ws_size,
                              hipStream_t stream) {
    const float* mlp  = (const float*)d_in[0];   // [B, T, H] fp32
    const float* attn = (const float*)d_in[1];   // [B, Hh, T, T] fp32
    float* out = (float*)d_out;                  // [B, T, H] fp32

    const int B = in_sizes[0] / (T_DIM * H_DIM); // = 2
    const int pairs = B * T_DIM / 2;             // 2048
    const int nblocks = pairs / 4;               // 512 blocks x 4 waves

    ctma_pipe_kernel<<<nblocks, 256, 0, stream>>>(mlp, attn, out);
}

// Round 11
// 104.654 us; speedup vs baseline: 1.0764x; 1.0764x over previous
//
#include <hip/hip_runtime.h>
#include <math.h>

#define K_TOP   8
#define EPS_F   1e-8f
#define T_DIM   2048
#define H_DIM   1024
#define NHEADS  16

typedef float f4 __attribute__((ext_vector_type(4)));

// One 64-lane wave per row. Packed f4 accumulation, half-head (4xf4)
// double-buffered prefetch to fit 128 VGPRs -> 4 blocks/CU (16 waves/CU).
// Top-k on sums (== top-k on means); inv16 folded into renorm scale.
// R10's gather-into-stream pipelining regressed (in-order vmcnt retire:
// HBM-miss gather loads stall later stream-prefetch consumption) — this
// R9 structure is the measured optimum (104.6 us ~= 85% read-stream BW).
__global__ __launch_bounds__(256, 4) void ctma_row_kernel(
    const float* __restrict__ mlp,   // [B, T, H]
    const float* __restrict__ attn,  // [B, Hh, T, T]
    float* __restrict__ out)         // [B, T, H]
{
    const int lane  = threadIdx.x & 63;
    const int wv_id = threadIdx.x >> 6;
    const int row   = blockIdx.x * 4 + wv_id;  // b*T + t
    const int b     = row >> 11;
    const int t     = row & (T_DIM - 1);

    const f4* a4 = reinterpret_cast<const f4*>(
        attn + (size_t)b * NHEADS * T_DIM * T_DIM + (size_t)t * T_DIM);
    const size_t hs4 = (size_t)T_DIM * T_DIM / 4;

    // ---------------- Phase 1: head-sum -> f4 registers ----------------
    // 32 half-head chunks; chunk c = (head h = c>>1, half p = c&1).
    // Chunk c covers row elements [p*1024, p*1024+1024): 4 f4 per lane.
    f4 accv[8];
    #pragma unroll
    for (int j = 0; j < 8; ++j) accv[j] = (f4)(0.0f);

    f4 tA[4], tB[4];
    // prefetch chunk 0
    #pragma unroll
    for (int j = 0; j < 4; ++j)
        tA[j] = __builtin_nontemporal_load(&a4[64 * j + lane]);

    #pragma unroll
    for (int c = 0; c < 32; ++c) {
        const int accbase = (c & 1) * 4;  // half p -> accv[4p..4p+3]
        if (c + 1 < 32) {
            const int hn = (c + 1) >> 1;
            const int pn = (c + 1) & 1;
            const f4* hp = a4 + (size_t)hn * hs4 + pn * 256;
            if (c & 1) {
                #pragma unroll
                for (int j = 0; j < 4; ++j)
                    tA[j] = __builtin_nontemporal_load(&hp[64 * j + lane]);
            } else {
                #pragma unroll
                for (int j = 0; j < 4; ++j)
                    tB[j] = __builtin_nontemporal_load(&hp[64 * j + lane]);
            }
        }
        if (c & 1) {
            #pragma unroll
            for (int j = 0; j < 4; ++j) accv[accbase + j] += tB[j];
        } else {
            #pragma unroll
            for (int j = 0; j < 4; ++j) accv[accbase + j] += tA[j];
        }
    }

    // ---------------- Phase 2: top-8 on sums ----------------
    // slot s (0..31): element e = 256*(s>>2) + 4*lane + (s&3), value accv[s>>2][s&3]
    float mybv = -INFINITY;
    int   mybi = 0x7fffffff;
    #pragma unroll
    for (int s = 0; s < 32; ++s) {
        const float val = accv[s >> 2][s & 3];
        if (val > mybv) { mybv = val; mybi = 256 * (s >> 2) + 4 * lane + (s & 3); }
    }
    unsigned mask = 0;

    float wvv[K_TOP];
    int   wii[K_TOP];

    for (int k = 0; k < K_TOP; ++k) {
        float bv = mybv;
        int   bi = mybi;
        #pragma unroll
        for (int off = 32; off > 0; off >>= 1) {
            const float ov = __shfl_down(bv, off);
            const int   oi = __shfl_down(bi, off);
            if (ov > bv || (ov == bv && oi < bi)) { bv = ov; bi = oi; }
        }
        bv = __shfl(bv, 0);
        bi = __shfl(bi, 0);
        wvv[k] = bv;
        wii[k] = bi;
        if (lane == ((bi >> 2) & 63)) {
            mask |= 1u << (4 * (bi >> 8) + (bi & 3));
            mybv = -INFINITY;
            mybi = 0x7fffffff;
            #pragma unroll
            for (int s = 0; s < 32; ++s) {
                const float val = ((mask >> s) & 1u) ? -INFINITY : accv[s >> 2][s & 3];
                if (val > mybv) { mybv = val; mybi = 256 * (s >> 2) + 4 * lane + (s & 3); }
            }
        }
    }

    // renorm: w_k = sum_k * (inv16 / max(sum*inv16, EPS))
    const float inv16 = 1.0f / (float)NHEADS;
    float wsum = 0.0f;
    #pragma unroll
    for (int k = 0; k < K_TOP; ++k) wsum += wvv[k];
    const float denom = fmaxf(wsum * inv16, EPS_F);
    const float scale = inv16 / denom;

    // ---------------- Phase 3: gather-weighted sum ----------------
    const f4* mlp4 = reinterpret_cast<const f4*>(mlp)
                   + (size_t)b * T_DIM * (H_DIM / 4);
    f4 o[4];
    #pragma unroll
    for (int j = 0; j < 4; ++j) o[j] = (f4)(0.0f);

    #pragma unroll
    for (int k = 0; k < K_TOP; ++k) {
        const float w = wvv[k] * scale;
        const f4* src = mlp4 + (size_t)wii[k] * (H_DIM / 4);
        #pragma unroll
        for (int j = 0; j < 4; ++j) {
            const f4 m = src[lane + 64 * j];
            o[j] += w * m;
        }
    }

    f4* out4 = reinterpret_cast<f4*>(out) + (size_t)row * (H_DIM / 4);
    #pragma unroll
    for (int j = 0; j < 4; ++j)
        __builtin_nontemporal_store(o[j], &out4[lane + 64 * j]);
}

extern "C" void kernel_launch(void* const* d_in, const int* in_sizes, int n_in,
                              void* d_out, int out_size, void* d_ws, size_t ws_size,
                              hipStream_t stream) {
    const float* mlp  = (const float*)d_in[0];   // [B, T, H] fp32
    const float* attn = (const float*)d_in[1];   // [B, Hh, T, T] fp32
    float* out = (float*)d_out;                  // [B, T, H] fp32

    const int B = in_sizes[0] / (T_DIM * H_DIM); // = 2
    const int rows = B * T_DIM;                  // 4096
    const int nblocks = rows / 4;                // 1024 blocks x 4 waves

    ctma_row_kernel<<<nblocks, 256, 0, stream>>>(mlp, attn, out);
}